// Round 6
// baseline (299.328 us; speedup 1.0000x reference)
//
#include <hip/hip_runtime.h>
#include <stdint.h>

typedef int v4i __attribute__((ext_vector_type(4)));
typedef int v16i __attribute__((ext_vector_type(16)));

#define GLD_LDS16(gp, lp)                                                              \
  __builtin_amdgcn_global_load_lds((const __attribute__((address_space(1))) void*)(gp), \
                                   (__attribute__((address_space(3))) void*)(lp), 16, 0, 0)

__device__ __forceinline__ v4i lds_read_b128(uint32_t off) {
  v4i r;
  asm volatile("ds_read_b128 %0, %1" : "=v"(r) : "v"(off));
  return r;
}

// ---------------------------------------------------------------------------
__device__ __forceinline__ void fwht16(float v[16]) {
#pragma unroll
  for (int h = 1; h < 16; h <<= 1) {
#pragma unroll
    for (int i = 0; i < 16; ++i) {
      if (!(i & h)) {
        float a = v[i], b = v[i | h];
        v[i] = a + b;
        v[i | h] = a - b;
      }
    }
  }
}

__device__ __forceinline__ void fwht_row_load(const float* __restrict__ xr, int t,
                                              float v[16]) {
  const float4* p = reinterpret_cast<const float4*>(xr) + t * 4;
  float4 a = p[0], b = p[1], c = p[2], d = p[3];
  v[0] = a.x; v[1] = a.y; v[2] = a.z; v[3] = a.w;
  v[4] = b.x; v[5] = b.y; v[6] = b.z; v[7] = b.w;
  v[8] = c.x; v[9] = c.y; v[10] = c.z; v[11] = c.w;
  v[12] = d.x; v[13] = d.y; v[14] = d.z; v[15] = d.w;
}

__device__ __forceinline__ void fwht4096(float v[16], float* lds, int t) {
  fwht16(v);
#pragma unroll
  for (int e = 0; e < 16; ++e) {
    int idx = t * 16 + e;
    lds[idx + (idx >> 5)] = v[e];
  }
  __syncthreads();
#pragma unroll
  for (int e = 0; e < 16; ++e) {
    int idx = ((t >> 4) << 8) + (e << 4) + (t & 15);
    v[e] = lds[idx + (idx >> 5)];
  }
  fwht16(v);
#pragma unroll
  for (int e = 0; e < 16; ++e) {
    int idx = ((t >> 4) << 8) + (e << 4) + (t & 15);
    lds[idx + (idx >> 5)] = v[e];
  }
  __syncthreads();
#pragma unroll
  for (int e = 0; e < 16; ++e) {
    int idx = (e << 8) + t;
    v[e] = lds[idx + (idx >> 5)];
  }
  fwht16(v);
#pragma unroll
  for (int e = 0; e < 16; ++e) v[e] *= 0.015625f;  // 1/sqrt(4096)
}

__global__ __launch_bounds__(256) void fwht_quant_kernel(const float* __restrict__ X,
                                                         int8_t* __restrict__ Q,
                                                         float* __restrict__ S) {
  const int row = blockIdx.x;
  const int t = threadIdx.x;
  __shared__ float lds[4224];
  __shared__ float wred[4];

  float v[16];
  fwht_row_load(X + (size_t)row * 4096, t, v);
  fwht4096(v, lds, t);

  float m = 0.f;
#pragma unroll
  for (int e = 0; e < 16; ++e) m = fmaxf(m, fabsf(v[e]));
#pragma unroll
  for (int off = 32; off > 0; off >>= 1) m = fmaxf(m, __shfl_xor(m, off));
  if ((t & 63) == 0) wred[t >> 6] = m;
  __syncthreads();
  m = fmaxf(fmaxf(wred[0], wred[1]), fmaxf(wred[2], wred[3]));
  const float s = fmaxf(m * (1.0f / 127.0f), 1e-8f);
  if (t == 0) S[row] = s;
  int8_t* qr = Q + (size_t)row * 4096;
#pragma unroll
  for (int e = 0; e < 16; ++e) {
    float q = rintf(v[e] / s);
    q = fminf(fmaxf(q, -127.f), 127.f);
    qr[(e << 8) + t] = (int8_t)(int)q;
  }
}

__global__ __launch_bounds__(256) void fwht_nq_kernel(const float* __restrict__ X,
                                                      float* __restrict__ F) {
  const int row = blockIdx.x;
  const int t = threadIdx.x;
  __shared__ float lds[4224];
  float v[16];
  fwht_row_load(X + (size_t)row * 4096, t, v);
  fwht4096(v, lds, t);
  float* fr = F + (size_t)row * 4096;
#pragma unroll
  for (int e = 0; e < 16; ++e) fr[(e << 8) + t] = v[e];
}

// ---------------------------------------------------------------------------
__global__ __launch_bounds__(256) void lora_t_partial_q(const int8_t* __restrict__ Qx,
                                                        const float* __restrict__ Sx,
                                                        const float* __restrict__ Ah,
                                                        float* __restrict__ tpart) {
  __shared__ float As[16][512];
  const int t = threadIdx.x;
  const int kc = blockIdx.y;
  const int row = blockIdx.x * 256 + t;
  for (int i = t; i < 2048; i += 256) {
    int r = i >> 7, c4 = i & 127;
    reinterpret_cast<float4*>(&As[r][0])[c4] =
        reinterpret_cast<const float4*>(Ah + (size_t)r * 4096 + kc * 512)[c4];
  }
  __syncthreads();
  float acc[16];
#pragma unroll
  for (int r = 0; r < 16; ++r) acc[r] = 0.f;
  const int8_t* xr = Qx + (size_t)row * 4096 + kc * 512;
  for (int k = 0; k < 512; k += 16) {
    int4 pv = *reinterpret_cast<const int4*>(xr + k);
    int us[4] = {pv.x, pv.y, pv.z, pv.w};
#pragma unroll
    for (int b = 0; b < 4; ++b) {
#pragma unroll
      for (int j = 0; j < 4; ++j) {
        float f = (float)((int)(int8_t)(us[b] >> (8 * j)));
        int kk = k + b * 4 + j;
#pragma unroll
        for (int r = 0; r < 16; ++r) acc[r] = fmaf(f, As[r][kk], acc[r]);
      }
    }
  }
  const float s = Sx[row];
  float* tp = tpart + ((size_t)kc * 8192 + row) * 16;
#pragma unroll
  for (int r = 0; r < 16; ++r) tp[r] = acc[r] * s;
}

__global__ __launch_bounds__(256) void lora_t_reduce_kernel(const float* __restrict__ tpart,
                                                            float* __restrict__ tmat) {
  int i = blockIdx.x * 256 + threadIdx.x;
  float s = 0.f;
#pragma unroll
  for (int kc = 0; kc < 8; ++kc) s += tpart[(size_t)kc * 131072 + i];
  tmat[i] = s;
}

// ---------------------------------------------------------------------------
// 256x128 i8 GEMM, mfma_i32_32x32x32_i8, 3-buffer ring (72 KB LDS -> 2
// blocks/CU, 4 waves/SIMD from two INDEPENDENT blocks), never-drain vmcnt(3).
// 8 waves = 4M x 2N; per-wave output 64x64 (acc = 2x2 v16i = 64 VGPR).
// Per step (BK=64B): stage(t+2) [3 gld_lds]; 8 ds_read_b128; lgkm(4);
// 4 MFMA (ks0); lgkm(0); 4 MFMA (ks1); vmcnt(3); barrier.
__global__ __launch_bounds__(512, 4) void gemm_i8_kernel(
    const int8_t* __restrict__ Aq, const int8_t* __restrict__ Bq,
    const float* __restrict__ Sx, const float* __restrict__ Sw,
    const float* __restrict__ Tm, const float* __restrict__ LB,
    float* __restrict__ out) {
  __shared__ __align__(16) char smem[73728];  // 3 x (A 16K + B 8K)

  const int tid = threadIdx.x;
  const int lane = tid & 63;
  const int w = tid >> 6;   // 0..7
  const int wm = w >> 1;    // 0..3
  const int wn = w & 1;     // 0..1

  int bid = (int)blockIdx.x;
  bid = (bid & 7) * 128 + (bid >> 3);  // bijective XCD swizzle (1024 % 8 == 0)
  const int bm = bid >> 5;             // 0..31
  const int bn = bid & 31;             // 0..31

  const int8_t* Ag = Aq + (size_t)bm * 256 * 4096;
  const int8_t* Bg = Bq + (size_t)bn * 128 * 4096;

  const uint32_t sbase = (uint32_t)(uintptr_t)(void*)smem;

  // ---- staging: 3 loads/wave/step; pre-swizzled source chunk ----
  const uint32_t srcOff = (uint32_t)(((lane & 3) ^ ((lane >> 3) & 3)) << 4);
  const uint32_t gA0 = (uint32_t)((w * 32 + (lane >> 2)) * 4096) + srcOff;
  const uint32_t gA1 = gA0 + 16 * 4096;
  const uint32_t gB0 = (uint32_t)((w * 16 + (lane >> 2)) * 4096) + srcOff;

#define STAGE_STEP(s, bufbase)                                           \
  do {                                                                   \
    const uint32_t kb = (uint32_t)(s) << 6;                              \
    GLD_LDS16(Ag + kb + gA0, smem + (bufbase) + w * 2048);               \
    GLD_LDS16(Ag + kb + gA1, smem + (bufbase) + w * 2048 + 1024);        \
    GLD_LDS16(Bg + kb + gB0, smem + (bufbase) + 16384 + w * 1024);       \
  } while (0)

  // ---- fragment LDS offsets: A frag (mt,ks), B frag (nt,ks) ----
  // 32x32x32 operand: row = lane&31, k-byte = (lane>>5)*16 + [0..16)
  int aoff[2][2], boff[2][2];
  const int swz = (lane >> 1) & 3;
  const int khalf = lane >> 5;
#pragma unroll
  for (int mt = 0; mt < 2; ++mt) {
    int r = wm * 64 + mt * 32 + (lane & 31);
#pragma unroll
    for (int ks = 0; ks < 2; ++ks) {
      int c = ((ks << 1) | khalf) ^ swz;
      aoff[mt][ks] = r * 64 + (c << 4);
    }
  }
#pragma unroll
  for (int nt = 0; nt < 2; ++nt) {
    int r = wn * 64 + nt * 32 + (lane & 31);
#pragma unroll
    for (int ks = 0; ks < 2; ++ks) {
      int c = ((ks << 1) | khalf) ^ swz;
      boff[nt][ks] = 16384 + r * 64 + (c << 4);
    }
  }

  v16i acc[2][2];
#pragma unroll
  for (int i = 0; i < 2; ++i)
#pragma unroll
    for (int n = 0; n < 2; ++n) {
      v16i z = {0};
      acc[i][n] = z;
    }

  // ---- prologue: stage steps 0,1 ----
  STAGE_STEP(0, 0);
  STAGE_STEP(1, 24576);
  asm volatile("s_waitcnt vmcnt(3)" ::: "memory");  // stage 0 landed
  __builtin_amdgcn_s_barrier();
  __builtin_amdgcn_sched_barrier(0);

  uint32_t bc = 0, bn1 = 24576, bn2 = 49152;

#pragma unroll 1
  for (int t = 0; t < 64; ++t) {
    if (t <= 61) STAGE_STEP(t + 2, bn2);

    const uint32_t R = sbase + bc;
    v4i a0[2], b0[2], a1[2], b1[2];
    b0[0] = lds_read_b128(R + boff[0][0]);
    b0[1] = lds_read_b128(R + boff[1][0]);
    a0[0] = lds_read_b128(R + aoff[0][0]);
    a0[1] = lds_read_b128(R + aoff[1][0]);
    b1[0] = lds_read_b128(R + boff[0][1]);
    b1[1] = lds_read_b128(R + boff[1][1]);
    a1[0] = lds_read_b128(R + aoff[0][1]);
    a1[1] = lds_read_b128(R + aoff[1][1]);

    asm volatile("s_waitcnt lgkmcnt(4)" ::: "memory");  // ks0 frags ready
    __builtin_amdgcn_sched_barrier(0);
    __builtin_amdgcn_s_setprio(1);
    acc[0][0] = __builtin_amdgcn_mfma_i32_32x32x32_i8(a0[0], b0[0], acc[0][0], 0, 0, 0);
    acc[0][1] = __builtin_amdgcn_mfma_i32_32x32x32_i8(a0[0], b0[1], acc[0][1], 0, 0, 0);
    acc[1][0] = __builtin_amdgcn_mfma_i32_32x32x32_i8(a0[1], b0[0], acc[1][0], 0, 0, 0);
    acc[1][1] = __builtin_amdgcn_mfma_i32_32x32x32_i8(a0[1], b0[1], acc[1][1], 0, 0, 0);
    __builtin_amdgcn_s_setprio(0);

    asm volatile("s_waitcnt lgkmcnt(0)" ::: "memory");  // ks1 frags ready
    __builtin_amdgcn_sched_barrier(0);
    __builtin_amdgcn_s_setprio(1);
    acc[0][0] = __builtin_amdgcn_mfma_i32_32x32x32_i8(a1[0], b1[0], acc[0][0], 0, 0, 0);
    acc[0][1] = __builtin_amdgcn_mfma_i32_32x32x32_i8(a1[0], b1[1], acc[0][1], 0, 0, 0);
    acc[1][0] = __builtin_amdgcn_mfma_i32_32x32x32_i8(a1[1], b1[0], acc[1][0], 0, 0, 0);
    acc[1][1] = __builtin_amdgcn_mfma_i32_32x32x32_i8(a1[1], b1[1], acc[1][1], 0, 0, 0);
    __builtin_amdgcn_s_setprio(0);

    // never-drain: wait stage(t+1) landed; t+2 stays in flight
    if (t <= 61)
      asm volatile("s_waitcnt vmcnt(3)" ::: "memory");
    else if (t == 62)
      asm volatile("s_waitcnt vmcnt(0)" ::: "memory");
    __builtin_amdgcn_s_barrier();
    __builtin_amdgcn_sched_barrier(0);

    uint32_t tmp = bc;  // ring rotate
    bc = bn1;
    bn1 = bn2;
    bn2 = tmp;
  }

  // ---- epilogue: scales + fused LoRA ----
  __syncthreads();
  float* tl = (float*)smem;              // [256][17]
  float* bl = (float*)(smem + 17408);    // [128][17]
  for (int i = tid; i < 1024; i += 512) {
    int r = i >> 2, q4 = (i & 3) * 4;
    float4 tv = *reinterpret_cast<const float4*>(Tm + (size_t)(bm * 256 + r) * 16 + q4);
    tl[r * 17 + q4 + 0] = tv.x;
    tl[r * 17 + q4 + 1] = tv.y;
    tl[r * 17 + q4 + 2] = tv.z;
    tl[r * 17 + q4 + 3] = tv.w;
  }
  for (int i = tid; i < 512; i += 512) {
    int r = i >> 2, q4 = (i & 3) * 4;
    float4 bv = *reinterpret_cast<const float4*>(LB + (size_t)(bn * 128 + r) * 16 + q4);
    bl[r * 17 + q4 + 0] = bv.x;
    bl[r * 17 + q4 + 1] = bv.y;
    bl[r * 17 + q4 + 2] = bv.z;
    bl[r * 17 + q4 + 3] = bv.w;
  }
  __syncthreads();

  float blv[2][16], swv[2];
#pragma unroll
  for (int nt = 0; nt < 2; ++nt) {
    int cl = wn * 64 + nt * 32 + (lane & 31);
    swv[nt] = Sw[bn * 128 + cl];
#pragma unroll
    for (int q = 0; q < 16; ++q) blv[nt][q] = bl[cl * 17 + q];
  }
#pragma unroll
  for (int mt = 0; mt < 2; ++mt) {
#pragma unroll
    for (int rg = 0; rg < 16; ++rg) {
      // C/D 32x32: row = (reg&3) + 8*(reg>>2) + 4*(lane>>5), col = lane&31
      int rl = wm * 64 + mt * 32 + (rg & 3) + 8 * (rg >> 2) + 4 * (lane >> 5);
      float sxv = Sx[bm * 256 + rl];
      float tv[16];
#pragma unroll
      for (int q = 0; q < 16; ++q) tv[q] = tl[rl * 17 + q];
      float* orow = out + (size_t)(bm * 256 + rl) * 4096 + bn * 128;
#pragma unroll
      for (int nt = 0; nt < 2; ++nt) {
        float dot = 0.f;
#pragma unroll
        for (int q = 0; q < 16; ++q) dot = fmaf(tv[q], blv[nt][q], dot);
        int cl = wn * 64 + nt * 32 + (lane & 31);
        orow[cl] = sxv * swv[nt] * (float)acc[mt][nt][rg] + 2.0f * dot;
      }
    }
  }
}

// ---------------------------------------------------------------------------
extern "C" void kernel_launch(void* const* d_in, const int* in_sizes, int n_in,
                              void* d_out, int out_size, void* d_ws, size_t ws_size,
                              hipStream_t stream) {
  const float* x = (const float*)d_in[0];     // 8192 x 4096
  const float* wgt = (const float*)d_in[1];   // 4096 x 4096
  const float* lA = (const float*)d_in[2];    // 16 x 4096
  const float* lB = (const float*)d_in[3];    // 4096 x 16
  float* out = (float*)d_out;                 // 8192 x 4096

  char* ws = (char*)d_ws;
  int8_t* qx = (int8_t*)ws;                    // 32 MB
  int8_t* qw = (int8_t*)(ws + 33554432);       // 16 MB
  float* sx = (float*)(ws + 50331648);         // 32 KB
  float* sw = (float*)(ws + 50364416);         // 16 KB
  float* tmat = (float*)(ws + 50380800);       // 512 KB
  float* tpart = (float*)(ws + 50905088);      // 4 MB
  float* Ah = (float*)(ws + 55099392);         // 256 KB

  fwht_quant_kernel<<<8192, 256, 0, stream>>>(x, qx, sx);
  fwht_quant_kernel<<<4096, 256, 0, stream>>>(wgt, qw, sw);
  fwht_nq_kernel<<<16, 256, 0, stream>>>(lA, Ah);
  lora_t_partial_q<<<dim3(32, 8), 256, 0, stream>>>(qx, sx, Ah, tpart);
  lora_t_reduce_kernel<<<512, 256, 0, stream>>>(tpart, tmat);
  gemm_i8_kernel<<<1024, 512, 0, stream>>>(qx, qw, sx, sw, tmat, lB, out);
}

// Round 7
// 294.707 us; speedup vs baseline: 1.0157x; 1.0157x over previous
//
#include <hip/hip_runtime.h>
#include <stdint.h>

typedef int v4i __attribute__((ext_vector_type(4)));
typedef int v16i __attribute__((ext_vector_type(16)));

#define GLD_LDS16(gp, lp)                                                              \
  __builtin_amdgcn_global_load_lds((const __attribute__((address_space(1))) void*)(gp), \
                                   (__attribute__((address_space(3))) void*)(lp), 16, 0, 0)

__device__ __forceinline__ v4i lds_read_b128(uint32_t off) {
  v4i r;
  asm volatile("ds_read_b128 %0, %1" : "=v"(r) : "v"(off));
  return r;
}

// ---------------------------------------------------------------------------
__device__ __forceinline__ void fwht16(float v[16]) {
#pragma unroll
  for (int h = 1; h < 16; h <<= 1) {
#pragma unroll
    for (int i = 0; i < 16; ++i) {
      if (!(i & h)) {
        float a = v[i], b = v[i | h];
        v[i] = a + b;
        v[i | h] = a - b;
      }
    }
  }
}

__device__ __forceinline__ void fwht_row_load(const float* __restrict__ xr, int t,
                                              float v[16]) {
  const float4* p = reinterpret_cast<const float4*>(xr) + t * 4;
  float4 a = p[0], b = p[1], c = p[2], d = p[3];
  v[0] = a.x; v[1] = a.y; v[2] = a.z; v[3] = a.w;
  v[4] = b.x; v[5] = b.y; v[6] = b.z; v[7] = b.w;
  v[8] = c.x; v[9] = c.y; v[10] = c.z; v[11] = c.w;
  v[12] = d.x; v[13] = d.y; v[14] = d.z; v[15] = d.w;
}

__device__ __forceinline__ void fwht4096(float v[16], float* lds, int t) {
  fwht16(v);
#pragma unroll
  for (int e = 0; e < 16; ++e) {
    int idx = t * 16 + e;
    lds[idx + (idx >> 5)] = v[e];
  }
  __syncthreads();
#pragma unroll
  for (int e = 0; e < 16; ++e) {
    int idx = ((t >> 4) << 8) + (e << 4) + (t & 15);
    v[e] = lds[idx + (idx >> 5)];
  }
  fwht16(v);
#pragma unroll
  for (int e = 0; e < 16; ++e) {
    int idx = ((t >> 4) << 8) + (e << 4) + (t & 15);
    lds[idx + (idx >> 5)] = v[e];
  }
  __syncthreads();
#pragma unroll
  for (int e = 0; e < 16; ++e) {
    int idx = (e << 8) + t;
    v[e] = lds[idx + (idx >> 5)];
  }
  fwht16(v);
#pragma unroll
  for (int e = 0; e < 16; ++e) v[e] *= 0.015625f;  // 1/sqrt(4096)
}

__global__ __launch_bounds__(256) void fwht_quant_kernel(const float* __restrict__ X,
                                                         int8_t* __restrict__ Q,
                                                         float* __restrict__ S) {
  const int row = blockIdx.x;
  const int t = threadIdx.x;
  __shared__ __align__(16) float lds[4224];
  __shared__ float wred[4];

  float v[16];
  fwht_row_load(X + (size_t)row * 4096, t, v);
  fwht4096(v, lds, t);

  float m = 0.f;
#pragma unroll
  for (int e = 0; e < 16; ++e) m = fmaxf(m, fabsf(v[e]));
#pragma unroll
  for (int off = 32; off > 0; off >>= 1) m = fmaxf(m, __shfl_xor(m, off));
  if ((t & 63) == 0) wred[t >> 6] = m;
  __syncthreads();
  m = fmaxf(fmaxf(wred[0], wred[1]), fmaxf(wred[2], wred[3]));
  const float s = fmaxf(m * (1.0f / 127.0f), 1e-8f);
  if (t == 0) S[row] = s;

  // quantize in regs, byte-transpose via padded LDS, one int4 store/thread.
  __syncthreads();  // phase-3 reads of lds complete
  char* b8 = (char*)lds;
#pragma unroll
  for (int e = 0; e < 16; ++e) {
    float q = rintf(v[e] / s);
    q = fminf(fmaxf(q, -127.f), 127.f);
    int idx = (e << 8) + t;
    b8[idx + ((idx >> 8) << 4)] = (char)(int)q;  // addr = e*272 + t
  }
  __syncthreads();
  int4 pack = *reinterpret_cast<const int4*>(b8 + t * 16 + ((t >> 4) << 4));
  reinterpret_cast<int4*>(Q + (size_t)row * 4096)[t] = pack;
}

__global__ __launch_bounds__(256) void fwht_nq_kernel(const float* __restrict__ X,
                                                      float* __restrict__ F) {
  const int row = blockIdx.x;
  const int t = threadIdx.x;
  __shared__ __align__(16) float lds[4224];
  float v[16];
  fwht_row_load(X + (size_t)row * 4096, t, v);
  fwht4096(v, lds, t);
  float* fr = F + (size_t)row * 4096;
#pragma unroll
  for (int e = 0; e < 16; ++e) fr[(e << 8) + t] = v[e];
}

// ---------------------------------------------------------------------------
__global__ __launch_bounds__(256) void lora_t_partial_q(const int8_t* __restrict__ Qx,
                                                        const float* __restrict__ Sx,
                                                        const float* __restrict__ Ah,
                                                        float* __restrict__ tpart) {
  __shared__ float As[16][512];
  const int t = threadIdx.x;
  const int kc = blockIdx.y;
  const int row = blockIdx.x * 256 + t;
  for (int i = t; i < 2048; i += 256) {
    int r = i >> 7, c4 = i & 127;
    reinterpret_cast<float4*>(&As[r][0])[c4] =
        reinterpret_cast<const float4*>(Ah + (size_t)r * 4096 + kc * 512)[c4];
  }
  __syncthreads();
  float acc[16];
#pragma unroll
  for (int r = 0; r < 16; ++r) acc[r] = 0.f;
  const int8_t* xr = Qx + (size_t)row * 4096 + kc * 512;
  for (int k = 0; k < 512; k += 16) {
    int4 pv = *reinterpret_cast<const int4*>(xr + k);
    int us[4] = {pv.x, pv.y, pv.z, pv.w};
#pragma unroll
    for (int b = 0; b < 4; ++b) {
#pragma unroll
      for (int j = 0; j < 4; ++j) {
        float f = (float)((int)(int8_t)(us[b] >> (8 * j)));
        int kk = k + b * 4 + j;
#pragma unroll
        for (int r = 0; r < 16; ++r) acc[r] = fmaf(f, As[r][kk], acc[r]);
      }
    }
  }
  const float s = Sx[row];
  float* tp = tpart + ((size_t)kc * 8192 + row) * 16;
#pragma unroll
  for (int r = 0; r < 16; ++r) tp[r] = acc[r] * s;
}

__global__ __launch_bounds__(256) void lora_t_reduce_kernel(const float* __restrict__ tpart,
                                                            float* __restrict__ tmat) {
  int i = blockIdx.x * 256 + threadIdx.x;
  float s = 0.f;
#pragma unroll
  for (int kc = 0; kc < 8; ++kc) s += tpart[(size_t)kc * 131072 + i];
  tmat[i] = s;
}

// ---------------------------------------------------------------------------
// 256x128 i8 GEMM, mfma_i32_32x32x32_i8, 3-buffer ring, never-drain vmcnt(3),
// CROSS-STEP REGISTER PIPELINE: ks0 fragments of step t+1 are ds_read right
// after the step-t barrier (hidden under the ks1 MFMA cluster), so every MFMA
// cluster starts with operands already in registers.
// Step layout:
//   stage(t+2); ds_read ks1(t); MFMA ks0 [preloaded]; lgkm(0);
//   vmcnt(3); s_barrier; ds_read ks0(t+1); MFMA ks1; lgkm(0)
__global__ __launch_bounds__(512, 2) void gemm_i8_kernel(
    const int8_t* __restrict__ Aq, const int8_t* __restrict__ Bq,
    const float* __restrict__ Sx, const float* __restrict__ Sw,
    const float* __restrict__ Tm, const float* __restrict__ LB,
    float* __restrict__ out) {
  __shared__ __align__(16) char smem[73728];  // 3 x (A 16K + B 8K)

  const int tid = threadIdx.x;
  const int lane = tid & 63;
  const int w = tid >> 6;   // 0..7
  const int wm = w >> 1;    // 0..3
  const int wn = w & 1;     // 0..1

  int bid = (int)blockIdx.x;
  bid = (bid & 7) * 128 + (bid >> 3);  // bijective XCD swizzle (1024 % 8 == 0)
  const int bm = bid >> 5;             // 0..31
  const int bn = bid & 31;             // 0..31

  const int8_t* Ag = Aq + (size_t)bm * 256 * 4096;
  const int8_t* Bg = Bq + (size_t)bn * 128 * 4096;

  const uint32_t sbase = (uint32_t)(uintptr_t)(void*)smem;

  // ---- staging: 3 loads/wave/step; pre-swizzled source chunk ----
  const uint32_t srcOff = (uint32_t)(((lane & 3) ^ ((lane >> 3) & 3)) << 4);
  const uint32_t gA0 = (uint32_t)((w * 32 + (lane >> 2)) * 4096) + srcOff;
  const uint32_t gA1 = gA0 + 16 * 4096;
  const uint32_t gB0 = (uint32_t)((w * 16 + (lane >> 2)) * 4096) + srcOff;

#define STAGE_STEP(s, bufbase)                                           \
  do {                                                                   \
    const uint32_t kb = (uint32_t)(s) << 6;                              \
    GLD_LDS16(Ag + kb + gA0, smem + (bufbase) + w * 2048);               \
    GLD_LDS16(Ag + kb + gA1, smem + (bufbase) + w * 2048 + 1024);        \
    GLD_LDS16(Bg + kb + gB0, smem + (bufbase) + 16384 + w * 1024);       \
  } while (0)

  // ---- fragment LDS offsets ----
  int aoff[2][2], boff[2][2];
  const int swz = (lane >> 1) & 3;
  const int khalf = lane >> 5;
#pragma unroll
  for (int mt = 0; mt < 2; ++mt) {
    int r = wm * 64 + mt * 32 + (lane & 31);
#pragma unroll
    for (int ks = 0; ks < 2; ++ks) {
      int c = ((ks << 1) | khalf) ^ swz;
      aoff[mt][ks] = r * 64 + (c << 4);
    }
  }
#pragma unroll
  for (int nt = 0; nt < 2; ++nt) {
    int r = wn * 64 + nt * 32 + (lane & 31);
#pragma unroll
    for (int ks = 0; ks < 2; ++ks) {
      int c = ((ks << 1) | khalf) ^ swz;
      boff[nt][ks] = 16384 + r * 64 + (c << 4);
    }
  }

  v16i acc[2][2];
#pragma unroll
  for (int i = 0; i < 2; ++i)
#pragma unroll
    for (int n = 0; n < 2; ++n) {
      v16i z = {0};
      acc[i][n] = z;
    }

  // ---- prologue: stage steps 0,1; preload ks0 frags of buf0 ----
  STAGE_STEP(0, 0);
  STAGE_STEP(1, 24576);
  asm volatile("s_waitcnt vmcnt(3)" ::: "memory");  // stage 0 landed (mine)
  __builtin_amdgcn_s_barrier();                     // -> all waves' stage 0 landed
  __builtin_amdgcn_sched_barrier(0);

  v4i a0c[2], b0c[2];
  b0c[0] = lds_read_b128(sbase + boff[0][0]);
  b0c[1] = lds_read_b128(sbase + boff[1][0]);
  a0c[0] = lds_read_b128(sbase + aoff[0][0]);
  a0c[1] = lds_read_b128(sbase + aoff[1][0]);
  asm volatile("s_waitcnt lgkmcnt(0)" ::: "memory");
  __builtin_amdgcn_sched_barrier(0);

  uint32_t bc = 0, bn1 = 24576, bn2 = 49152;

#pragma unroll 1
  for (int t = 0; t < 64; ++t) {
    if (t <= 61) STAGE_STEP(t + 2, bn2);

    const uint32_t R = sbase + bc;
    v4i a1[2], b1[2];
    b1[0] = lds_read_b128(R + boff[0][1]);
    b1[1] = lds_read_b128(R + boff[1][1]);
    a1[0] = lds_read_b128(R + aoff[0][1]);
    a1[1] = lds_read_b128(R + aoff[1][1]);

    // ks0 cluster: operands preloaded last step -> no wait
    __builtin_amdgcn_s_setprio(1);
    acc[0][0] = __builtin_amdgcn_mfma_i32_32x32x32_i8(a0c[0], b0c[0], acc[0][0], 0, 0, 0);
    acc[0][1] = __builtin_amdgcn_mfma_i32_32x32x32_i8(a0c[0], b0c[1], acc[0][1], 0, 0, 0);
    acc[1][0] = __builtin_amdgcn_mfma_i32_32x32x32_i8(a0c[1], b0c[0], acc[1][0], 0, 0, 0);
    acc[1][1] = __builtin_amdgcn_mfma_i32_32x32x32_i8(a0c[1], b0c[1], acc[1][1], 0, 0, 0);
    __builtin_amdgcn_s_setprio(0);
    asm volatile("s_waitcnt lgkmcnt(0)" ::: "memory");  // ks1 frags ready
    __builtin_amdgcn_sched_barrier(0);

    // publish: stage(t+1) landed everywhere; buf t reads all done (issued above)
    if (t <= 61)
      asm volatile("s_waitcnt vmcnt(3)" ::: "memory");
    else if (t == 62)
      asm volatile("s_waitcnt vmcnt(0)" ::: "memory");
    __builtin_amdgcn_sched_barrier(0);
    __builtin_amdgcn_s_barrier();

    // preload ks0 of buf(t+1): latency hides under ks1 cluster
    if (t < 63) {
      const uint32_t Rn = sbase + bn1;
      b0c[0] = lds_read_b128(Rn + boff[0][0]);
      b0c[1] = lds_read_b128(Rn + boff[1][0]);
      a0c[0] = lds_read_b128(Rn + aoff[0][0]);
      a0c[1] = lds_read_b128(Rn + aoff[1][0]);
    }

    __builtin_amdgcn_s_setprio(1);
    acc[0][0] = __builtin_amdgcn_mfma_i32_32x32x32_i8(a1[0], b1[0], acc[0][0], 0, 0, 0);
    acc[0][1] = __builtin_amdgcn_mfma_i32_32x32x32_i8(a1[0], b1[1], acc[0][1], 0, 0, 0);
    acc[1][0] = __builtin_amdgcn_mfma_i32_32x32x32_i8(a1[1], b1[0], acc[1][0], 0, 0, 0);
    acc[1][1] = __builtin_amdgcn_mfma_i32_32x32x32_i8(a1[1], b1[1], acc[1][1], 0, 0, 0);
    __builtin_amdgcn_s_setprio(0);
    if (t < 63) {
      asm volatile("s_waitcnt lgkmcnt(0)" ::: "memory");  // next ks0 ready
      __builtin_amdgcn_sched_barrier(0);
    }

    uint32_t tmp = bc;  // ring rotate
    bc = bn1;
    bn1 = bn2;
    bn2 = tmp;
  }

  // ---- epilogue: scales + fused LoRA ----
  __syncthreads();
  float* tl = (float*)smem;              // [256][17]
  float* bl = (float*)(smem + 17408);    // [128][17]
  for (int i = tid; i < 1024; i += 512) {
    int r = i >> 2, q4 = (i & 3) * 4;
    float4 tv = *reinterpret_cast<const float4*>(Tm + (size_t)(bm * 256 + r) * 16 + q4);
    tl[r * 17 + q4 + 0] = tv.x;
    tl[r * 17 + q4 + 1] = tv.y;
    tl[r * 17 + q4 + 2] = tv.z;
    tl[r * 17 + q4 + 3] = tv.w;
  }
  for (int i = tid; i < 512; i += 512) {
    int r = i >> 2, q4 = (i & 3) * 4;
    float4 bv = *reinterpret_cast<const float4*>(LB + (size_t)(bn * 128 + r) * 16 + q4);
    bl[r * 17 + q4 + 0] = bv.x;
    bl[r * 17 + q4 + 1] = bv.y;
    bl[r * 17 + q4 + 2] = bv.z;
    bl[r * 17 + q4 + 3] = bv.w;
  }
  __syncthreads();

  float blv[2][16], swv[2];
#pragma unroll
  for (int nt = 0; nt < 2; ++nt) {
    int cl = wn * 64 + nt * 32 + (lane & 31);
    swv[nt] = Sw[bn * 128 + cl];
#pragma unroll
    for (int q = 0; q < 16; ++q) blv[nt][q] = bl[cl * 17 + q];
  }
#pragma unroll
  for (int mt = 0; mt < 2; ++mt) {
#pragma unroll
    for (int rg = 0; rg < 16; ++rg) {
      // C/D 32x32: row = (reg&3) + 8*(reg>>2) + 4*(lane>>5), col = lane&31
      int rl = wm * 64 + mt * 32 + (rg & 3) + 8 * (rg >> 2) + 4 * (lane >> 5);
      float sxv = Sx[bm * 256 + rl];
      float tv[16];
#pragma unroll
      for (int q = 0; q < 16; ++q) tv[q] = tl[rl * 17 + q];
      float* orow = out + (size_t)(bm * 256 + rl) * 4096 + bn * 128;
#pragma unroll
      for (int nt = 0; nt < 2; ++nt) {
        float dot = 0.f;
#pragma unroll
        for (int q = 0; q < 16; ++q) dot = fmaf(tv[q], blv[nt][q], dot);
        int cl = wn * 64 + nt * 32 + (lane & 31);
        orow[cl] = sxv * swv[nt] * (float)acc[mt][nt][rg] + 2.0f * dot;
      }
    }
  }
}

// ---------------------------------------------------------------------------
extern "C" void kernel_launch(void* const* d_in, const int* in_sizes, int n_in,
                              void* d_out, int out_size, void* d_ws, size_t ws_size,
                              hipStream_t stream) {
  const float* x = (const float*)d_in[0];     // 8192 x 4096
  const float* wgt = (const float*)d_in[1];   // 4096 x 4096
  const float* lA = (const float*)d_in[2];    // 16 x 4096
  const float* lB = (const float*)d_in[3];    // 4096 x 16
  float* out = (float*)d_out;                 // 8192 x 4096

  char* ws = (char*)d_ws;
  int8_t* qx = (int8_t*)ws;                    // 32 MB
  int8_t* qw = (int8_t*)(ws + 33554432);       // 16 MB
  float* sx = (float*)(ws + 50331648);         // 32 KB
  float* sw = (float*)(ws + 50364416);         // 16 KB
  float* tmat = (float*)(ws + 50380800);       // 512 KB
  float* tpart = (float*)(ws + 50905088);      // 4 MB
  float* Ah = (float*)(ws + 55099392);         // 256 KB

  fwht_quant_kernel<<<8192, 256, 0, stream>>>(x, qx, sx);
  fwht_quant_kernel<<<4096, 256, 0, stream>>>(wgt, qw, sw);
  fwht_nq_kernel<<<16, 256, 0, stream>>>(lA, Ah);
  lora_t_partial_q<<<dim3(32, 8), 256, 0, stream>>>(qx, sx, Ah, tpart);
  lora_t_reduce_kernel<<<512, 256, 0, stream>>>(tpart, tmat);
  gemm_i8_kernel<<<1024, 512, 0, stream>>>(qx, qw, sx, sw, tmat, lB, out);
}